// Round 8
// baseline (667.831 us; speedup 1.0000x reference)
//
#include <hip/hip_runtime.h>
#include <hip/hip_cooperative_groups.h>

namespace cg = cooperative_groups;

#define N_NODES 100000
#define E_EDGES 1600000
#define D 128
#define FCHUNK 2048
#define NCHUNK 782          // ceil(E/FCHUNK)
#define NIDX (NCHUNK * 8)   // 6256 fill work items
#define RSIZE 12500         // nodes per XCD range (N/8)
#define GRID 768            // >=98 for scan, %8==0 for fill mapping, 3 blocks/CU exact
#define NTILES 1563         // (N+63)/64 gemm tiles
#define PADK 72             // LDS k-stride (ushorts)

typedef __attribute__((ext_vector_type(8))) short short8;
typedef __attribute__((ext_vector_type(8))) unsigned short ushort8v;
typedef __attribute__((ext_vector_type(4))) float f32x4;

// ---------- threefry2x32, key=(0,42), ctr=(0,i); JAX partitionable 32-bit: x0^x1 ----------
__device__ __forceinline__ unsigned int rotl32(unsigned int x, int r) {
  return (x << r) | (x >> (32 - r));
}

__device__ __forceinline__ unsigned int threefry_bits(unsigned int ctr) {
  const unsigned int ks0 = 0u, ks1 = 42u;
  const unsigned int ks2 = ks0 ^ ks1 ^ 0x1BD11BDAu;
  unsigned int x0 = ks0;
  unsigned int x1 = ctr + ks1;
#define TF_ROUND(R) { x0 += x1; x1 = rotl32(x1, R); x1 ^= x0; }
  TF_ROUND(13) TF_ROUND(15) TF_ROUND(26) TF_ROUND(6)
  x0 += ks1; x1 += ks2 + 1u;
  TF_ROUND(17) TF_ROUND(29) TF_ROUND(16) TF_ROUND(24)
  x0 += ks2; x1 += ks0 + 2u;
  TF_ROUND(13) TF_ROUND(15) TF_ROUND(26) TF_ROUND(6)
  x0 += ks0; x1 += ks1 + 3u;
  TF_ROUND(17) TF_ROUND(29) TF_ROUND(16) TF_ROUND(24)
  x0 += ks1; x1 += ks2 + 4u;
  TF_ROUND(13) TF_ROUND(15) TF_ROUND(26) TF_ROUND(6)
  x0 += ks2; x1 += ks0 + 5u;
#undef TF_ROUND
  return x0 ^ x1;
}

__device__ __forceinline__ unsigned short f2bf(float f) {
  unsigned int u = __float_as_uint(f);
  u = (u + 0x7FFFu + ((u >> 16) & 1u)) >> 16;   // RNE
  return (unsigned short)u;
}
__device__ __forceinline__ float bf2f_lo(unsigned int v) {
  return __uint_as_float(v << 16);
}
__device__ __forceinline__ float bf2f_hi(unsigned int v) {
  return __uint_as_float(v & 0xFFFF0000u);
}

// ================= shared phase bodies =================

__device__ __forceinline__ void gemm_tiles(const float* __restrict__ x,
                                           const float* __restrict__ w,
                                           unsigned short* __restrict__ h,
                                           unsigned short* Wl, unsigned short* Xl,
                                           int t, int tile0, int tstride) {
  const int wv   = t >> 6;
  const int l    = t & 63;
  const int quad = l >> 4;
  const int ln16 = l & 15;
  const int m0   = wv * 16;
  const float4* x4 = (const float4*)x;

  for (int tile = tile0; tile < NTILES; tile += tstride) {
    const int row0 = tile * 64;
    f32x4 acc[8];
#pragma unroll
    for (int nt = 0; nt < 8; ++nt) acc[nt] = (f32x4){0.f, 0.f, 0.f, 0.f};

    for (int p = 0; p < 2; ++p) {
      __syncthreads();   // prev readers of LDS done
#pragma unroll
      for (int i = 0; i < 4; ++i) {
        int u  = t + i * 256;          // 0..1023
        int n  = u & 127;
        int kg = u >> 7;               // 0..7
        ushort8v pk;
#pragma unroll
        for (int j = 0; j < 8; ++j)
          pk[j] = (short)f2bf(w[(p * 64 + kg * 8 + j) * D + n]);
        *(ushort8v*)&Wl[n * PADK + kg * 8] = pk;
      }
#pragma unroll
      for (int i = 0; i < 4; ++i) {
        int id = t + i * 256;          // 0..1023
        int r  = id >> 4;              // 0..63
        int c4 = id & 15;              // 0..15
        int row = row0 + r; if (row >= N_NODES) row = N_NODES - 1;
        float4 v = x4[(long long)row * 32 + p * 16 + c4];
        ushort4 pkt;
        pkt.x = f2bf(v.x); pkt.y = f2bf(v.y); pkt.z = f2bf(v.z); pkt.w = f2bf(v.w);
        *(ushort4*)&Xl[r * PADK + c4 * 4] = pkt;
      }
      __syncthreads();

      short8 a[2];
#pragma unroll
      for (int kt = 0; kt < 2; ++kt)
        a[kt] = *(const short8*)&Xl[(m0 + ln16) * PADK + kt * 32 + quad * 8];
#pragma unroll
      for (int nt = 0; nt < 8; ++nt) {
#pragma unroll
        for (int kt = 0; kt < 2; ++kt) {
          short8 bb = *(const short8*)&Wl[(nt * 16 + ln16) * PADK + kt * 32 + quad * 8];
          acc[nt] = __builtin_amdgcn_mfma_f32_16x16x32_bf16(a[kt], bb, acc[nt], 0, 0, 0);
        }
      }
    }
#pragma unroll
    for (int nt = 0; nt < 8; ++nt) {
#pragma unroll
      for (int r = 0; r < 4; ++r) {
        int row = row0 + m0 + quad * 4 + r;
        if (row < N_NODES)
          h[(long long)row * D + nt * 16 + ln16] = f2bf(acc[nt][r]);
      }
    }
  }
}

__device__ __forceinline__ void scan1_body(const int* __restrict__ deg,
                                           int* __restrict__ part,
                                           int* __restrict__ bsum,
                                           int* sm, int t, int b) {
  int base = b * 1024 + t * 4;
  int v[4]; int s = 0;
#pragma unroll
  for (int q = 0; q < 4; ++q) { v[q] = (base + q < N_NODES) ? deg[base + q] : 0; s += v[q]; }
  sm[t] = s; __syncthreads();
  for (int off = 1; off < 256; off <<= 1) {
    int xx = (t >= off) ? sm[t - off] : 0;
    __syncthreads();
    sm[t] += xx;
    __syncthreads();
  }
  int run = sm[t] - s;
#pragma unroll
  for (int q = 0; q < 4; ++q) {
    if (base + q < N_NODES) part[base + q] = run;
    run += v[q];
  }
  if (t == 255) bsum[b] = sm[255];
}

__device__ __forceinline__ void scan3_body(const int* __restrict__ part,
                                           const int* __restrict__ bsum,
                                           int* __restrict__ rowptr,
                                           int* __restrict__ cursor,
                                           int* __restrict__ deg,
                                           int* sm, int t, int b) {
  if (t < 128) sm[t] = (t < b) ? bsum[t] : 0;
  __syncthreads();
  for (int ww = 64; ww > 0; ww >>= 1) {
    if (t < ww) sm[t] += sm[t + ww];
    __syncthreads();
  }
  int off = sm[0];
  int base = b * 1024 + t * 4;
#pragma unroll
  for (int q = 0; q < 4; ++q) {
    int i = base + q;
    if (i < N_NODES) {
      int r = part[i] + off;
      rowptr[i] = r;
      cursor[i] = r;
      deg[i] = __float_as_int(rsqrtf((float)(deg[i] + 1)));  // dinv in place
    }
  }
  if (b == 0 && t == 0) rowptr[N_NODES] = E_EDGES;
}

__device__ __forceinline__ void fill_body(const int* __restrict__ ei,
                                          const int* __restrict__ dinv_bits,
                                          int* __restrict__ cursor,
                                          int2* __restrict__ srcw,
                                          int t, int b, int stride) {
  const int* dst = ei + E_EDGES;
  const int r  = b & 7;
  const int lo = r * RSIZE;
  const int hi = lo + RSIZE;
  for (int idx = b; idx < NIDX; idx += stride) {   // stride%8==0 keeps r per-block
    int base = (idx >> 3) * FCHUNK;
#pragma unroll
    for (int i = 0; i < FCHUNK / 256; ++i) {
      int e = base + i * 256 + t;
      if (e < E_EDGES) {
        int d = dst[e];
        if (d >= lo && d < hi) {
          int s = ei[e];
          int pos = atomicAdd(&cursor[d], 1);
          srcw[pos] = make_int2(s, dinv_bits[s]);
        }
      }
    }
  }
}

// ================= cooperative mega-kernel =================
__global__ __launch_bounds__(256, 4) void k_coop(const float* __restrict__ x,
                                                 const float* __restrict__ w,
                                                 unsigned short* __restrict__ h,
                                                 const int* __restrict__ ei,
                                                 int* __restrict__ deg,
                                                 int* __restrict__ part,
                                                 int* __restrict__ bsum,
                                                 int* __restrict__ rowptr,
                                                 int* __restrict__ cursor,
                                                 int2* __restrict__ srcw) {
  __shared__ unsigned short Wl[128 * PADK];
  __shared__ unsigned short Xl[64 * PADK];
  __shared__ int sm[256];
  cg::grid_group grid = cg::this_grid();
  const int t = threadIdx.x;
  const int b = blockIdx.x;
  const int gtid = b * 256 + t;
  const int* dst = ei + E_EDGES;

  for (int i = gtid; i < N_NODES; i += GRID * 256) deg[i] = 0;
  grid.sync();

  for (int e = gtid; e < E_EDGES; e += GRID * 256) atomicAdd(&deg[dst[e]], 1);
  gemm_tiles(x, w, h, Wl, Xl, t, b, GRID);
  grid.sync();

  if (b < 98) scan1_body(deg, part, bsum, sm, t, b);
  grid.sync();

  if (b < 98) scan3_body(part, bsum, rowptr, cursor, deg, sm, t, b);
  grid.sync();

  fill_body(ei, deg, cursor, srcw, t, b, GRID);
}

// ================= discrete fallback kernels =================
__global__ __launch_bounds__(256) void k_deg_f(const int* __restrict__ dst,
                                               int* __restrict__ deg) {
  int e = blockIdx.x * 256 + threadIdx.x;
  if (e < E_EDGES) atomicAdd(&deg[dst[e]], 1);
}

__global__ __launch_bounds__(256) void k_gemm_f(const float* __restrict__ x,
                                                const float* __restrict__ w,
                                                unsigned short* __restrict__ h) {
  __shared__ unsigned short Wl[128 * PADK];
  __shared__ unsigned short Xl[64 * PADK];
  gemm_tiles(x, w, h, Wl, Xl, threadIdx.x, blockIdx.x, NTILES + 1);
}

__global__ __launch_bounds__(256) void k_scan1_f(const int* __restrict__ deg,
                                                 int* __restrict__ part,
                                                 int* __restrict__ bsum) {
  __shared__ int sm[256];
  scan1_body(deg, part, bsum, sm, threadIdx.x, blockIdx.x);
}

__global__ __launch_bounds__(256) void k_scan3_f(const int* __restrict__ part,
                                                 const int* __restrict__ bsum,
                                                 int* __restrict__ rowptr,
                                                 int* __restrict__ cursor,
                                                 int* __restrict__ deg) {
  __shared__ int sm[256];
  scan3_body(part, bsum, rowptr, cursor, deg, sm, threadIdx.x, blockIdx.x);
}

__global__ __launch_bounds__(256) void k_fill_f(const int* __restrict__ ei,
                                                const int* __restrict__ dinv_bits,
                                                int* __restrict__ cursor,
                                                int2* __restrict__ srcw) {
  fill_body(ei, dinv_bits, cursor, srcw, threadIdx.x, blockIdx.x, NIDX + 8);
}

// ---------- aggregate: quarter-wave per edge, 2 edges in flight, fused epilogue ----------
__global__ __launch_bounds__(256) void k_agg(const int* __restrict__ rowptr,
                                             const int2* __restrict__ srcw,
                                             const float* __restrict__ dinv,
                                             const unsigned short* __restrict__ h,
                                             const float* __restrict__ bias,
                                             float* __restrict__ out) {
  const int t = threadIdx.x;
  const int n = blockIdx.x * 4 + (t >> 6);
  const int lane = t & 63;
  const int q  = lane >> 4;
  const int li = lane & 15;
  const uint4* hq = (const uint4*)h;
  float dn = dinv[n];
  int e1 = rowptr[n + 1];
  float accA[8], accB[8];
#pragma unroll
  for (int j = 0; j < 8; ++j) { accA[j] = 0.f; accB[j] = 0.f; }

  for (int e = rowptr[n] + q; e < e1; e += 8) {
    int2 sw = srcw[e];
    float wgt = __int_as_float(sw.y) * dn;
    uint4 v = hq[(long long)sw.x * 16 + li];
    int e2 = e + 4;
    if (e2 < e1) {
      int2 sw2 = srcw[e2];
      float wgt2 = __int_as_float(sw2.y) * dn;
      uint4 v2 = hq[(long long)sw2.x * 16 + li];
      accB[0] = fmaf(bf2f_lo(v2.x), wgt2, accB[0]);
      accB[1] = fmaf(bf2f_hi(v2.x), wgt2, accB[1]);
      accB[2] = fmaf(bf2f_lo(v2.y), wgt2, accB[2]);
      accB[3] = fmaf(bf2f_hi(v2.y), wgt2, accB[3]);
      accB[4] = fmaf(bf2f_lo(v2.z), wgt2, accB[4]);
      accB[5] = fmaf(bf2f_hi(v2.z), wgt2, accB[5]);
      accB[6] = fmaf(bf2f_lo(v2.w), wgt2, accB[6]);
      accB[7] = fmaf(bf2f_hi(v2.w), wgt2, accB[7]);
    }
    accA[0] = fmaf(bf2f_lo(v.x), wgt, accA[0]);
    accA[1] = fmaf(bf2f_hi(v.x), wgt, accA[1]);
    accA[2] = fmaf(bf2f_lo(v.y), wgt, accA[2]);
    accA[3] = fmaf(bf2f_hi(v.y), wgt, accA[3]);
    accA[4] = fmaf(bf2f_lo(v.z), wgt, accA[4]);
    accA[5] = fmaf(bf2f_hi(v.z), wgt, accA[5]);
    accA[6] = fmaf(bf2f_lo(v.w), wgt, accA[6]);
    accA[7] = fmaf(bf2f_hi(v.w), wgt, accA[7]);
  }
#pragma unroll
  for (int j = 0; j < 8; ++j) {
    float a = accA[j] + accB[j];
    a += __shfl_xor(a, 16);
    a += __shfl_xor(a, 32);
    accA[j] = a;
  }
  float a0 = accA[q * 2];
  float a1 = accA[q * 2 + 1];
  unsigned int hv = ((const unsigned int*)h)[(long long)n * 64 + li * 4 + q];
  float w2 = dn * dn;
  a0 = fmaf(bf2f_lo(hv), w2, a0);
  a1 = fmaf(bf2f_hi(hv), w2, a1);
  float2 bb = ((const float2*)bias)[li * 4 + q];
  float r0 = fmaxf(a0 + bb.x, 0.f);
  float r1 = fmaxf(a1 + bb.y, 0.f);
  unsigned int i0 = (unsigned int)n * 128u + (unsigned int)(li * 8 + q * 2);
  unsigned int b0 = threefry_bits(i0);
  unsigned int b1 = threefry_bits(i0 + 1u);
  float2 res;
  res.x = (b0 & 0x80000000u) ? 0.0f : r0 * 2.0f;
  res.y = (b1 & 0x80000000u) ? 0.0f : r1 * 2.0f;
  ((float2*)out)[(long long)n * 64 + li * 4 + q] = res;
}

extern "C" void kernel_launch(void* const* d_in, const int* in_sizes, int n_in,
                              void* d_out, int out_size, void* d_ws, size_t ws_size,
                              hipStream_t stream) {
  const float* x    = (const float*)d_in[0];
  const int*   ei   = (const int*)d_in[1];
  const float* w    = (const float*)d_in[2];
  const float* bias = (const float*)d_in[3];
  float* out = (float*)d_out;

  char* p = (char*)d_ws;
  unsigned short* h = (unsigned short*)p;   p += (size_t)N_NODES * D * 2;  // 25.6 MB
  int*  deg    = (int*)p;                   p += (size_t)N_NODES * 4;      // dinv after scan3
  int*  rowptr = (int*)p;                   p += (size_t)(N_NODES + 1) * 4;
  int*  cursor = (int*)p;                   p += (size_t)N_NODES * 4;
  int*  part   = (int*)p;                   p += (size_t)N_NODES * 4;
  int*  bsum   = (int*)p;                   p += 128 * 4;
  int2* srcw   = (int2*)p;                  p += (size_t)E_EDGES * 8;      // 12.8 MB

  void* args[] = {(void*)&x, (void*)&w, (void*)&h, (void*)&ei, (void*)&deg,
                  (void*)&part, (void*)&bsum, (void*)&rowptr, (void*)&cursor,
                  (void*)&srcw};
  hipError_t err = hipLaunchCooperativeKernel((void*)k_coop, dim3(GRID), dim3(256),
                                              args, 0, stream);
  if (err != hipSuccess) {
    // discrete fallback (proven R5 pipeline)
    hipMemsetAsync(deg, 0, (size_t)N_NODES * 4, stream);
    k_deg_f<<<(E_EDGES + 255) / 256, 256, 0, stream>>>(ei + E_EDGES, deg);
    k_gemm_f<<<NTILES, 256, 0, stream>>>(x, w, h);
    k_scan1_f<<<98, 256, 0, stream>>>(deg, part, bsum);
    k_scan3_f<<<98, 256, 0, stream>>>(part, bsum, rowptr, cursor, deg);
    k_fill_f<<<NIDX, 256, 0, stream>>>(ei, deg, cursor, srcw);
  }
  const float* dinv = (const float*)deg;
  k_agg<<<N_NODES / 4, 256, 0, stream>>>(rowptr, srcw, dinv, h, bias, out);
}

// Round 9
// 343.784 us; speedup vs baseline: 1.9426x; 1.9426x over previous
//
#include <hip/hip_runtime.h>

#define N_NODES 100000
#define E_EDGES 1600000
#define D 128
#define FCHUNK 2048
#define NCHUNK 782          // ceil(E/FCHUNK)
#define NIDX (NCHUNK * 8)   // 6256 fill blocks
#define RSIZE 12500         // nodes per XCD range (N/8)
#define NTILES 1563         // (N+63)/64 gemm tiles
#define DEG_BLKS 6250       // E/256
#define PADK 72             // LDS k-stride (ushorts)

typedef __attribute__((ext_vector_type(8))) short short8;
typedef __attribute__((ext_vector_type(8))) unsigned short ushort8v;
typedef __attribute__((ext_vector_type(4))) float f32x4;
#if __has_builtin(__builtin_amdgcn_fdot2_f32_bf16)
typedef __attribute__((ext_vector_type(2))) __bf16 bf16x2;
#define USE_DOT2 1
#else
#define USE_DOT2 0
#endif

// ---------- threefry2x32, key=(0,42), ctr=(0,i); JAX partitionable 32-bit: x0^x1 ----------
__device__ __forceinline__ unsigned int rotl32(unsigned int x, int r) {
  return (x << r) | (x >> (32 - r));
}

__device__ __forceinline__ unsigned int threefry_bits(unsigned int ctr) {
  const unsigned int ks0 = 0u, ks1 = 42u;
  const unsigned int ks2 = ks0 ^ ks1 ^ 0x1BD11BDAu;
  unsigned int x0 = ks0;
  unsigned int x1 = ctr + ks1;
#define TF_ROUND(R) { x0 += x1; x1 = rotl32(x1, R); x1 ^= x0; }
  TF_ROUND(13) TF_ROUND(15) TF_ROUND(26) TF_ROUND(6)
  x0 += ks1; x1 += ks2 + 1u;
  TF_ROUND(17) TF_ROUND(29) TF_ROUND(16) TF_ROUND(24)
  x0 += ks2; x1 += ks0 + 2u;
  TF_ROUND(13) TF_ROUND(15) TF_ROUND(26) TF_ROUND(6)
  x0 += ks0; x1 += ks1 + 3u;
  TF_ROUND(17) TF_ROUND(29) TF_ROUND(16) TF_ROUND(24)
  x0 += ks1; x1 += ks2 + 4u;
  TF_ROUND(13) TF_ROUND(15) TF_ROUND(26) TF_ROUND(6)
  x0 += ks2; x1 += ks0 + 5u;
#undef TF_ROUND
  return x0 ^ x1;
}

__device__ __forceinline__ unsigned short f2bf(float f) {
  unsigned int u = __float_as_uint(f);
  u = (u + 0x7FFFu + ((u >> 16) & 1u)) >> 16;   // RNE
  return (unsigned short)u;
}
__device__ __forceinline__ float bf2f_lo(unsigned int v) {
  return __uint_as_float(v << 16);
}
__device__ __forceinline__ float bf2f_hi(unsigned int v) {
  return __uint_as_float(v & 0xFFFF0000u);
}

// ---------- fused: gemm tiles (blocks < NTILES) + deg histogram (rest) ----------
__global__ __launch_bounds__(256) void k_pre(const float* __restrict__ x,
                                             const float* __restrict__ w,
                                             unsigned short* __restrict__ h,
                                             const int* __restrict__ dst,
                                             int* __restrict__ deg) {
  __shared__ unsigned short Wl[128 * PADK];   // 18.4 KB
  __shared__ unsigned short Xl[64 * PADK];    //  9.2 KB
  const int t = threadIdx.x;

  if (blockIdx.x >= NTILES) {
    int e = (blockIdx.x - NTILES) * 256 + t;
    if (e < E_EDGES) atomicAdd(&deg[dst[e]], 1);
    return;
  }

  const int row0 = blockIdx.x * 64;
  const int wv   = t >> 6;
  const int l    = t & 63;
  const int quad = l >> 4;
  const int ln16 = l & 15;
  const int m0   = wv * 16;
  const float4* x4 = (const float4*)x;

  f32x4 acc[8];
#pragma unroll
  for (int nt = 0; nt < 8; ++nt) acc[nt] = (f32x4){0.f, 0.f, 0.f, 0.f};

  for (int p = 0; p < 2; ++p) {
    __syncthreads();
#pragma unroll
    for (int i = 0; i < 4; ++i) {
      int u  = t + i * 256;          // 0..1023
      int n  = u & 127;
      int kg = u >> 7;               // 0..7
      ushort8v pk;
#pragma unroll
      for (int j = 0; j < 8; ++j)
        pk[j] = (short)f2bf(w[(p * 64 + kg * 8 + j) * D + n]);
      *(ushort8v*)&Wl[n * PADK + kg * 8] = pk;
    }
#pragma unroll
    for (int i = 0; i < 4; ++i) {
      int id = t + i * 256;          // 0..1023
      int r  = id >> 4;              // 0..63
      int c4 = id & 15;              // 0..15
      int row = row0 + r; if (row >= N_NODES) row = N_NODES - 1;
      float4 v = x4[(long long)row * 32 + p * 16 + c4];
      ushort4 pkt;
      pkt.x = f2bf(v.x); pkt.y = f2bf(v.y); pkt.z = f2bf(v.z); pkt.w = f2bf(v.w);
      *(ushort4*)&Xl[r * PADK + c4 * 4] = pkt;
    }
    __syncthreads();

    short8 a[2];
#pragma unroll
    for (int kt = 0; kt < 2; ++kt)
      a[kt] = *(const short8*)&Xl[(m0 + ln16) * PADK + kt * 32 + quad * 8];
#pragma unroll
    for (int nt = 0; nt < 8; ++nt) {
#pragma unroll
      for (int kt = 0; kt < 2; ++kt) {
        short8 bb = *(const short8*)&Wl[(nt * 16 + ln16) * PADK + kt * 32 + quad * 8];
        acc[nt] = __builtin_amdgcn_mfma_f32_16x16x32_bf16(a[kt], bb, acc[nt], 0, 0, 0);
      }
    }
  }
#pragma unroll
  for (int nt = 0; nt < 8; ++nt) {
#pragma unroll
    for (int r = 0; r < 4; ++r) {
      int row = row0 + m0 + quad * 4 + r;
      if (row < N_NODES)
        h[(long long)row * D + nt * 16 + ln16] = f2bf(acc[nt][r]);
    }
  }
}

// ---------- fused scan: scan1 + device barrier (98 co-resident blocks) + scan3 ----------
__global__ __launch_bounds__(256) void k_scan(int* __restrict__ deg,
                                              int* __restrict__ part,
                                              int* __restrict__ bsum,
                                              int* __restrict__ bar,
                                              int* __restrict__ rowptr,
                                              int* __restrict__ cursor) {
  __shared__ int sm[256];
  const int t = threadIdx.x, b = blockIdx.x;
  // --- phase 1: per-block exclusive scan of 1024 deg ---
  int base = b * 1024 + t * 4;
  int v[4]; int s = 0;
#pragma unroll
  for (int q = 0; q < 4; ++q) { v[q] = (base + q < N_NODES) ? deg[base + q] : 0; s += v[q]; }
  sm[t] = s; __syncthreads();
  for (int off = 1; off < 256; off <<= 1) {
    int xx = (t >= off) ? sm[t - off] : 0;
    __syncthreads();
    sm[t] += xx;
    __syncthreads();
  }
  int run = sm[t] - s;
#pragma unroll
  for (int q = 0; q < 4; ++q) {
    if (base + q < N_NODES) part[base + q] = run;
    run += v[q];
  }
  int total = sm[255];
  // --- device barrier: 98 blocks <= 256 CUs are co-resident -> safe spin ---
  if (t == 0) {
    __hip_atomic_store(&bsum[b], total, __ATOMIC_RELEASE, __HIP_MEMORY_SCOPE_AGENT);
    __hip_atomic_fetch_add(bar, 1, __ATOMIC_RELEASE, __HIP_MEMORY_SCOPE_AGENT);
    while (__hip_atomic_load(bar, __ATOMIC_ACQUIRE, __HIP_MEMORY_SCOPE_AGENT) < 98)
      __builtin_amdgcn_s_sleep(2);
  }
  __syncthreads();
  // --- phase 2: offset = sum of bsum[0..b-1]; rowptr/cursor/dinv ---
  if (t < 128)
    sm[t] = (t < b) ? __hip_atomic_load(&bsum[t], __ATOMIC_ACQUIRE, __HIP_MEMORY_SCOPE_AGENT) : 0;
  __syncthreads();
  for (int ww = 64; ww > 0; ww >>= 1) {
    if (t < ww) sm[t] += sm[t + ww];
    __syncthreads();
  }
  int off = sm[0];
#pragma unroll
  for (int q = 0; q < 4; ++q) {
    int i = base + q;
    if (i < N_NODES) {
      int r = part[i] + off;
      rowptr[i] = r;
      cursor[i] = r;
      deg[i] = __float_as_int(rsqrtf((float)(deg[i] + 1)));  // dinv in place
    }
  }
  if (b == 0 && t == 0) rowptr[N_NODES] = E_EDGES;
}

// ---------- fill CSR, XCD-range partitioned ----------
__global__ __launch_bounds__(256) void k_fill(const int* __restrict__ ei,
                                              const int* __restrict__ dinv_bits,
                                              int* __restrict__ cursor,
                                              int2* __restrict__ srcw) {
  const int* dst = ei + E_EDGES;
  const int r  = blockIdx.x & 7;
  const int lo = r * RSIZE;
  const int hi = lo + RSIZE;
  const int base = (blockIdx.x >> 3) * FCHUNK;
#pragma unroll
  for (int i = 0; i < FCHUNK / 256; ++i) {
    int e = base + i * 256 + threadIdx.x;
    if (e < E_EDGES) {
      int d = dst[e];
      if (d >= lo && d < hi) {
        int s = ei[e];
        int pos = atomicAdd(&cursor[d], 1);
        srcw[pos] = make_int2(s, dinv_bits[s]);
      }
    }
  }
}

// ---------- aggregate: quarter-wave per edge, dot2 over edge pairs, fused epilogue ----------
__global__ __launch_bounds__(256) void k_agg(const int* __restrict__ rowptr,
                                             const int2* __restrict__ srcw,
                                             const float* __restrict__ dinv,
                                             const unsigned short* __restrict__ h,
                                             const float* __restrict__ bias,
                                             float* __restrict__ out) {
  const int t = threadIdx.x;
  const int n = blockIdx.x * 4 + (t >> 6);
  const int lane = t & 63;
  const int q  = lane >> 4;
  const int li = lane & 15;
  const uint4* hq = (const uint4*)h;
  float dn = dinv[n];
  int e1 = rowptr[n + 1];
  float acc[8];
#pragma unroll
  for (int j = 0; j < 8; ++j) acc[j] = 0.f;

  for (int e = rowptr[n] + q; e < e1; e += 8) {
    long long swA = __builtin_nontemporal_load((const long long*)(srcw + e));
    int   sA = (int)swA;
    float wA = __int_as_float((int)(swA >> 32)) * dn;
    uint4 vA = hq[(long long)sA * 16 + li];
    int e2 = e + 4;
    if (e2 < e1) {
      long long swB = __builtin_nontemporal_load((const long long*)(srcw + e2));
      int   sB = (int)swB;
      float wB = __int_as_float((int)(swB >> 32)) * dn;
      uint4 vB = hq[(long long)sB * 16 + li];
#if USE_DOT2
      unsigned int wp = (unsigned int)f2bf(wA) | ((unsigned int)f2bf(wB) << 16);
      bf16x2 wv = __builtin_bit_cast(bf16x2, wp);
      unsigned int uA[4] = {vA.x, vA.y, vA.z, vA.w};
      unsigned int uB[4] = {vB.x, vB.y, vB.z, vB.w};
#pragma unroll
      for (int j = 0; j < 4; ++j) {
        unsigned int plo = __builtin_amdgcn_perm(uB[j], uA[j], 0x05040100u); // (A_lo,B_lo)
        unsigned int phi = __builtin_amdgcn_perm(uB[j], uA[j], 0x07060302u); // (A_hi,B_hi)
        acc[2 * j]     = __builtin_amdgcn_fdot2_f32_bf16(__builtin_bit_cast(bf16x2, plo), wv, acc[2 * j], false);
        acc[2 * j + 1] = __builtin_amdgcn_fdot2_f32_bf16(__builtin_bit_cast(bf16x2, phi), wv, acc[2 * j + 1], false);
      }
#else
      acc[0] = fmaf(bf2f_lo(vA.x), wA, fmaf(bf2f_lo(vB.x), wB, acc[0]));
      acc[1] = fmaf(bf2f_hi(vA.x), wA, fmaf(bf2f_hi(vB.x), wB, acc[1]));
      acc[2] = fmaf(bf2f_lo(vA.y), wA, fmaf(bf2f_lo(vB.y), wB, acc[2]));
      acc[3] = fmaf(bf2f_hi(vA.y), wA, fmaf(bf2f_hi(vB.y), wB, acc[3]));
      acc[4] = fmaf(bf2f_lo(vA.z), wA, fmaf(bf2f_lo(vB.z), wB, acc[4]));
      acc[5] = fmaf(bf2f_hi(vA.z), wA, fmaf(bf2f_hi(vB.z), wB, acc[5]));
      acc[6] = fmaf(bf2f_lo(vA.w), wA, fmaf(bf2f_lo(vB.w), wB, acc[6]));
      acc[7] = fmaf(bf2f_hi(vA.w), wA, fmaf(bf2f_hi(vB.w), wB, acc[7]));
#endif
    } else {
      acc[0] = fmaf(bf2f_lo(vA.x), wA, acc[0]);
      acc[1] = fmaf(bf2f_hi(vA.x), wA, acc[1]);
      acc[2] = fmaf(bf2f_lo(vA.y), wA, acc[2]);
      acc[3] = fmaf(bf2f_hi(vA.y), wA, acc[3]);
      acc[4] = fmaf(bf2f_lo(vA.z), wA, acc[4]);
      acc[5] = fmaf(bf2f_hi(vA.z), wA, acc[5]);
      acc[6] = fmaf(bf2f_lo(vA.w), wA, acc[6]);
      acc[7] = fmaf(bf2f_hi(vA.w), wA, acc[7]);
    }
  }
#pragma unroll
  for (int j = 0; j < 8; ++j) {
    float a = acc[j];
    a += __shfl_xor(a, 16);
    a += __shfl_xor(a, 32);
    acc[j] = a;
  }
  float a0 = acc[q * 2];
  float a1 = acc[q * 2 + 1];
  unsigned int hv = ((const unsigned int*)h)[(long long)n * 64 + li * 4 + q];
  float w2 = dn * dn;
  a0 = fmaf(bf2f_lo(hv), w2, a0);
  a1 = fmaf(bf2f_hi(hv), w2, a1);
  float2 bb = ((const float2*)bias)[li * 4 + q];
  float r0 = fmaxf(a0 + bb.x, 0.f);
  float r1 = fmaxf(a1 + bb.y, 0.f);
  unsigned int i0 = (unsigned int)n * 128u + (unsigned int)(li * 8 + q * 2);
  unsigned int b0 = threefry_bits(i0);
  unsigned int b1 = threefry_bits(i0 + 1u);
  float rx = (b0 & 0x80000000u) ? 0.0f : r0 * 2.0f;
  float ry = (b1 & 0x80000000u) ? 0.0f : r1 * 2.0f;
  unsigned long long pack = (unsigned long long)__float_as_uint(rx) |
                            ((unsigned long long)__float_as_uint(ry) << 32);
  __builtin_nontemporal_store(pack,
      (unsigned long long*)((float2*)out + (long long)n * 64 + li * 4 + q));
}

extern "C" void kernel_launch(void* const* d_in, const int* in_sizes, int n_in,
                              void* d_out, int out_size, void* d_ws, size_t ws_size,
                              hipStream_t stream) {
  const float* x    = (const float*)d_in[0];
  const int*   ei   = (const int*)d_in[1];
  const float* w    = (const float*)d_in[2];
  const float* bias = (const float*)d_in[3];
  float* out = (float*)d_out;

  char* p = (char*)d_ws;
  unsigned short* h = (unsigned short*)p;   p += (size_t)N_NODES * D * 2;  // 25.6 MB
  int*  deg    = (int*)p;                   p += (size_t)N_NODES * 4;      // dinv after scan
  int*  bar    = (int*)p;                   p += 4 * 4;                    // barrier ctr (+pad)
  int*  rowptr = (int*)p;                   p += (size_t)(N_NODES + 1) * 4;
  int*  cursor = (int*)p;                   p += (size_t)N_NODES * 4;
  int*  part   = (int*)p;                   p += (size_t)N_NODES * 4;
  int*  bsum   = (int*)p;                   p += 128 * 4;
  int2* srcw   = (int2*)p;                  p += (size_t)E_EDGES * 8;      // 12.8 MB

  // zero deg + barrier counter in one memset
  hipMemsetAsync(deg, 0, (size_t)(N_NODES + 4) * 4, stream);

  k_pre<<<NTILES + DEG_BLKS, 256, 0, stream>>>(x, w, h, ei + E_EDGES, deg);
  k_scan<<<98, 256, 0, stream>>>(deg, part, bsum, bar, rowptr, cursor);
  k_fill<<<NIDX, 256, 0, stream>>>(ei, deg, cursor, srcw);
  const float* dinv = (const float*)deg;
  k_agg<<<N_NODES / 4, 256, 0, stream>>>(rowptr, srcw, dinv, h, bias, out);
}

// Round 10
// 330.223 us; speedup vs baseline: 2.0224x; 1.0411x over previous
//
#include <hip/hip_runtime.h>

#define N_NODES 100000
#define E_EDGES 1600000
#define D 128
#define FCHUNK 2048
#define NCHUNK 782          // ceil(E/FCHUNK)
#define NIDX (NCHUNK * 8)   // 6256 fill blocks
#define RSIZE 12500         // nodes per XCD range (N/8)
#define NTILES 1563         // (N+63)/64 gemm tiles
#define DEG_BLKS 6250       // E/256
#define PADK 72             // LDS k-stride (ushorts)

typedef __attribute__((ext_vector_type(8))) short short8;
typedef __attribute__((ext_vector_type(8))) unsigned short ushort8v;
typedef __attribute__((ext_vector_type(4))) float f32x4;
#if __has_builtin(__builtin_amdgcn_fdot2_f32_bf16)
typedef __attribute__((ext_vector_type(2))) __bf16 bf16x2;
#define USE_DOT2 1
#else
#define USE_DOT2 0
#endif

// ---------- threefry2x32, key=(0,42), ctr=(0,i); JAX partitionable 32-bit: x0^x1 ----------
__device__ __forceinline__ unsigned int rotl32(unsigned int x, int r) {
  return (x << r) | (x >> (32 - r));
}

__device__ __forceinline__ unsigned int threefry_bits(unsigned int ctr) {
  const unsigned int ks0 = 0u, ks1 = 42u;
  const unsigned int ks2 = ks0 ^ ks1 ^ 0x1BD11BDAu;
  unsigned int x0 = ks0;
  unsigned int x1 = ctr + ks1;
#define TF_ROUND(R) { x0 += x1; x1 = rotl32(x1, R); x1 ^= x0; }
  TF_ROUND(13) TF_ROUND(15) TF_ROUND(26) TF_ROUND(6)
  x0 += ks1; x1 += ks2 + 1u;
  TF_ROUND(17) TF_ROUND(29) TF_ROUND(16) TF_ROUND(24)
  x0 += ks2; x1 += ks0 + 2u;
  TF_ROUND(13) TF_ROUND(15) TF_ROUND(26) TF_ROUND(6)
  x0 += ks0; x1 += ks1 + 3u;
  TF_ROUND(17) TF_ROUND(29) TF_ROUND(16) TF_ROUND(24)
  x0 += ks1; x1 += ks2 + 4u;
  TF_ROUND(13) TF_ROUND(15) TF_ROUND(26) TF_ROUND(6)
  x0 += ks2; x1 += ks0 + 5u;
#undef TF_ROUND
  return x0 ^ x1;
}

__device__ __forceinline__ unsigned short f2bf(float f) {
  unsigned int u = __float_as_uint(f);
  u = (u + 0x7FFFu + ((u >> 16) & 1u)) >> 16;   // RNE
  return (unsigned short)u;
}
__device__ __forceinline__ float bf2f_lo(unsigned int v) {
  return __uint_as_float(v << 16);
}
__device__ __forceinline__ float bf2f_hi(unsigned int v) {
  return __uint_as_float(v & 0xFFFF0000u);
}

// ---------- init: zero deg + barrier, convert W to bf16 (once, not per gemm block) ----------
__global__ __launch_bounds__(256) void k_init(const float* __restrict__ w,
                                              unsigned short* __restrict__ wbf,
                                              int* __restrict__ deg,
                                              int* __restrict__ bar) {
  int i = blockIdx.x * 256 + threadIdx.x;   // grid 392*256 = 100352 >= N_NODES
  if (i < D * D) wbf[i] = f2bf(w[i]);
  if (i < N_NODES) deg[i] = 0;
  if (i == 0) *bar = 0;
}

// ---------- fused: gemm tiles (blocks < NTILES) + deg histogram (rest) ----------
__global__ __launch_bounds__(256) void k_pre(const float* __restrict__ x,
                                             const unsigned short* __restrict__ wbf,
                                             unsigned short* __restrict__ h,
                                             const int* __restrict__ dst,
                                             int* __restrict__ deg) {
  __shared__ unsigned short Wl[128 * PADK];   // 18.4 KB
  __shared__ unsigned short Xl[64 * PADK];    //  9.2 KB
  const int t = threadIdx.x;

  if (blockIdx.x >= NTILES) {
    int e = (blockIdx.x - NTILES) * 256 + t;
    if (e < E_EDGES) atomicAdd(&deg[dst[e]], 1);
    return;
  }

  const int row0 = blockIdx.x * 64;
  const int wv   = t >> 6;
  const int l    = t & 63;
  const int quad = l >> 4;
  const int ln16 = l & 15;
  const int m0   = wv * 16;
  const float4* x4 = (const float4*)x;

  f32x4 acc[8];
#pragma unroll
  for (int nt = 0; nt < 8; ++nt) acc[nt] = (f32x4){0.f, 0.f, 0.f, 0.f};

  for (int p = 0; p < 2; ++p) {
    __syncthreads();
    // stage W half (already bf16): transpose [k][n] -> [n][k]
#pragma unroll
    for (int i = 0; i < 4; ++i) {
      int u  = t + i * 256;          // 0..1023
      int n  = u & 127;
      int kg = u >> 7;               // 0..7
      ushort8v pk;
#pragma unroll
      for (int j = 0; j < 8; ++j)
        pk[j] = wbf[(p * 64 + kg * 8 + j) * D + n];
      *(ushort8v*)&Wl[n * PADK + kg * 8] = pk;
    }
    // stage X half: 64 rows x 64 k, fp32 -> bf16
#pragma unroll
    for (int i = 0; i < 4; ++i) {
      int id = t + i * 256;          // 0..1023
      int r  = id >> 4;              // 0..63
      int c4 = id & 15;              // 0..15
      int row = row0 + r; if (row >= N_NODES) row = N_NODES - 1;
      float4 v = x4[(long long)row * 32 + p * 16 + c4];
      ushort4 pkt;
      pkt.x = f2bf(v.x); pkt.y = f2bf(v.y); pkt.z = f2bf(v.z); pkt.w = f2bf(v.w);
      *(ushort4*)&Xl[r * PADK + c4 * 4] = pkt;
    }
    __syncthreads();

    short8 a[2];
#pragma unroll
    for (int kt = 0; kt < 2; ++kt)
      a[kt] = *(const short8*)&Xl[(m0 + ln16) * PADK + kt * 32 + quad * 8];
#pragma unroll
    for (int nt = 0; nt < 8; ++nt) {
#pragma unroll
      for (int kt = 0; kt < 2; ++kt) {
        short8 bb = *(const short8*)&Wl[(nt * 16 + ln16) * PADK + kt * 32 + quad * 8];
        acc[nt] = __builtin_amdgcn_mfma_f32_16x16x32_bf16(a[kt], bb, acc[nt], 0, 0, 0);
      }
    }
  }
#pragma unroll
  for (int nt = 0; nt < 8; ++nt) {
#pragma unroll
    for (int r = 0; r < 4; ++r) {
      int row = row0 + m0 + quad * 4 + r;
      if (row < N_NODES)
        h[(long long)row * D + nt * 16 + ln16] = f2bf(acc[nt][r]);
    }
  }
}

// ---------- fused scan: scan1 + device barrier (98 co-resident blocks) + scan3 ----------
__global__ __launch_bounds__(256) void k_scan(int* __restrict__ deg,
                                              int* __restrict__ part,
                                              int* __restrict__ bsum,
                                              int* __restrict__ bar,
                                              int* __restrict__ rowptr,
                                              int* __restrict__ cursor) {
  __shared__ int sm[256];
  const int t = threadIdx.x, b = blockIdx.x;
  int base = b * 1024 + t * 4;
  int v[4]; int s = 0;
#pragma unroll
  for (int q = 0; q < 4; ++q) { v[q] = (base + q < N_NODES) ? deg[base + q] : 0; s += v[q]; }
  sm[t] = s; __syncthreads();
  for (int off = 1; off < 256; off <<= 1) {
    int xx = (t >= off) ? sm[t - off] : 0;
    __syncthreads();
    sm[t] += xx;
    __syncthreads();
  }
  int run = sm[t] - s;
#pragma unroll
  for (int q = 0; q < 4; ++q) {
    if (base + q < N_NODES) part[base + q] = run;
    run += v[q];
  }
  int total = sm[255];
  // device barrier: 98 blocks <= 256 CUs, unconditionally co-resident -> safe spin
  if (t == 0) {
    __hip_atomic_store(&bsum[b], total, __ATOMIC_RELEASE, __HIP_MEMORY_SCOPE_AGENT);
    __hip_atomic_fetch_add(bar, 1, __ATOMIC_RELEASE, __HIP_MEMORY_SCOPE_AGENT);
    while (__hip_atomic_load(bar, __ATOMIC_ACQUIRE, __HIP_MEMORY_SCOPE_AGENT) < 98)
      __builtin_amdgcn_s_sleep(2);
  }
  __syncthreads();
  if (t < 128)
    sm[t] = (t < b) ? __hip_atomic_load(&bsum[t], __ATOMIC_ACQUIRE, __HIP_MEMORY_SCOPE_AGENT) : 0;
  __syncthreads();
  for (int ww = 64; ww > 0; ww >>= 1) {
    if (t < ww) sm[t] += sm[t + ww];
    __syncthreads();
  }
  int off = sm[0];
#pragma unroll
  for (int q = 0; q < 4; ++q) {
    int i = base + q;
    if (i < N_NODES) {
      int r = part[i] + off;
      rowptr[i] = r;
      cursor[i] = r;
      deg[i] = __float_as_int(rsqrtf((float)(deg[i] + 1)));  // dinv in place
    }
  }
  if (b == 0 && t == 0) rowptr[N_NODES] = E_EDGES;
}

// ---------- fill CSR (src only, 4B), XCD-range partitioned ----------
__global__ __launch_bounds__(256) void k_fill(const int* __restrict__ ei,
                                              int* __restrict__ cursor,
                                              int* __restrict__ srcs) {
  const int* dst = ei + E_EDGES;
  const int r  = blockIdx.x & 7;
  const int lo = r * RSIZE;
  const int hi = lo + RSIZE;
  const int base = (blockIdx.x >> 3) * FCHUNK;
#pragma unroll
  for (int i = 0; i < FCHUNK / 256; ++i) {
    int e = base + i * 256 + threadIdx.x;
    if (e < E_EDGES) {
      int d = dst[e];
      if (d >= lo && d < hi) {
        int pos = atomicAdd(&cursor[d], 1);
        srcs[pos] = ei[e];
      }
    }
  }
}

// ---------- aggregate: quarter-wave per edge, dot2 pairs, fused epilogue ----------
__global__ __launch_bounds__(256) void k_agg(const int* __restrict__ rowptr,
                                             const int* __restrict__ srcs,
                                             const float* __restrict__ dinv,
                                             const unsigned short* __restrict__ h,
                                             const float* __restrict__ bias,
                                             float* __restrict__ out) {
  const int t = threadIdx.x;
  const int n = blockIdx.x * 4 + (t >> 6);
  const int lane = t & 63;
  const int q  = lane >> 4;
  const int li = lane & 15;
  const uint4* hq = (const uint4*)h;
  float dn = dinv[n];
  int e1 = rowptr[n + 1];
  float acc[8];
#pragma unroll
  for (int j = 0; j < 8; ++j) acc[j] = 0.f;

  for (int e = rowptr[n] + q; e < e1; e += 8) {
    int   sA = srcs[e];
    float wA = dinv[sA] * dn;
    uint4 vA = hq[(long long)sA * 16 + li];
    int e2 = e + 4;
    if (e2 < e1) {
      int   sB = srcs[e2];
      float wB = dinv[sB] * dn;
      uint4 vB = hq[(long long)sB * 16 + li];
#if USE_DOT2
      unsigned int wp = (unsigned int)f2bf(wA) | ((unsigned int)f2bf(wB) << 16);
      bf16x2 wv = __builtin_bit_cast(bf16x2, wp);
      unsigned int uA[4] = {vA.x, vA.y, vA.z, vA.w};
      unsigned int uB[4] = {vB.x, vB.y, vB.z, vB.w};
#pragma unroll
      for (int j = 0; j < 4; ++j) {
        unsigned int plo = __builtin_amdgcn_perm(uB[j], uA[j], 0x05040100u); // (A_lo,B_lo)
        unsigned int phi = __builtin_amdgcn_perm(uB[j], uA[j], 0x07060302u); // (A_hi,B_hi)
        acc[2 * j]     = __builtin_amdgcn_fdot2_f32_bf16(__builtin_bit_cast(bf16x2, plo), wv, acc[2 * j], false);
        acc[2 * j + 1] = __builtin_amdgcn_fdot2_f32_bf16(__builtin_bit_cast(bf16x2, phi), wv, acc[2 * j + 1], false);
      }
#else
      acc[0] = fmaf(bf2f_lo(vA.x), wA, fmaf(bf2f_lo(vB.x), wB, acc[0]));
      acc[1] = fmaf(bf2f_hi(vA.x), wA, fmaf(bf2f_hi(vB.x), wB, acc[1]));
      acc[2] = fmaf(bf2f_lo(vA.y), wA, fmaf(bf2f_lo(vB.y), wB, acc[2]));
      acc[3] = fmaf(bf2f_hi(vA.y), wA, fmaf(bf2f_hi(vB.y), wB, acc[3]));
      acc[4] = fmaf(bf2f_lo(vA.z), wA, fmaf(bf2f_lo(vB.z), wB, acc[4]));
      acc[5] = fmaf(bf2f_hi(vA.z), wA, fmaf(bf2f_hi(vB.z), wB, acc[5]));
      acc[6] = fmaf(bf2f_lo(vA.w), wA, fmaf(bf2f_lo(vB.w), wB, acc[6]));
      acc[7] = fmaf(bf2f_hi(vA.w), wA, fmaf(bf2f_hi(vB.w), wB, acc[7]));
#endif
    } else {
      acc[0] = fmaf(bf2f_lo(vA.x), wA, acc[0]);
      acc[1] = fmaf(bf2f_hi(vA.x), wA, acc[1]);
      acc[2] = fmaf(bf2f_lo(vA.y), wA, acc[2]);
      acc[3] = fmaf(bf2f_hi(vA.y), wA, acc[3]);
      acc[4] = fmaf(bf2f_lo(vA.z), wA, acc[4]);
      acc[5] = fmaf(bf2f_hi(vA.z), wA, acc[5]);
      acc[6] = fmaf(bf2f_lo(vA.w), wA, acc[6]);
      acc[7] = fmaf(bf2f_hi(vA.w), wA, acc[7]);
    }
  }
#pragma unroll
  for (int j = 0; j < 8; ++j) {
    float a = acc[j];
    a += __shfl_xor(a, 16);
    a += __shfl_xor(a, 32);
    acc[j] = a;
  }
  float a0 = acc[q * 2];
  float a1 = acc[q * 2 + 1];
  unsigned int hv = ((const unsigned int*)h)[(long long)n * 64 + li * 4 + q];
  float w2 = dn * dn;
  a0 = fmaf(bf2f_lo(hv), w2, a0);
  a1 = fmaf(bf2f_hi(hv), w2, a1);
  float2 bb = ((const float2*)bias)[li * 4 + q];
  float r0 = fmaxf(a0 + bb.x, 0.f);
  float r1 = fmaxf(a1 + bb.y, 0.f);
  unsigned int i0 = (unsigned int)n * 128u + (unsigned int)(li * 8 + q * 2);
  unsigned int b0 = threefry_bits(i0);
  unsigned int b1 = threefry_bits(i0 + 1u);
  float rx = (b0 & 0x80000000u) ? 0.0f : r0 * 2.0f;
  float ry = (b1 & 0x80000000u) ? 0.0f : r1 * 2.0f;
  unsigned long long pack = (unsigned long long)__float_as_uint(rx) |
                            ((unsigned long long)__float_as_uint(ry) << 32);
  __builtin_nontemporal_store(pack,
      (unsigned long long*)((float2*)out + (long long)n * 64 + li * 4 + q));
}

extern "C" void kernel_launch(void* const* d_in, const int* in_sizes, int n_in,
                              void* d_out, int out_size, void* d_ws, size_t ws_size,
                              hipStream_t stream) {
  const float* x    = (const float*)d_in[0];
  const int*   ei   = (const int*)d_in[1];
  const float* w    = (const float*)d_in[2];
  const float* bias = (const float*)d_in[3];
  float* out = (float*)d_out;

  char* p = (char*)d_ws;
  unsigned short* h   = (unsigned short*)p;  p += (size_t)N_NODES * D * 2;  // 25.6 MB
  unsigned short* wbf = (unsigned short*)p;  p += (size_t)D * D * 2;        // 32 KB
  int*  deg    = (int*)p;                    p += (size_t)N_NODES * 4;      // dinv after scan
  int*  bar    = (int*)p;                    p += 4 * 4;
  int*  rowptr = (int*)p;                    p += (size_t)(N_NODES + 1) * 4;
  int*  cursor = (int*)p;                    p += (size_t)N_NODES * 4;
  int*  part   = (int*)p;                    p += (size_t)N_NODES * 4;
  int*  bsum   = (int*)p;                    p += 128 * 4;
  int*  srcs   = (int*)p;                    p += (size_t)E_EDGES * 4;      // 6.4 MB

  k_init<<<392, 256, 0, stream>>>(w, wbf, deg, bar);
  k_pre<<<NTILES + DEG_BLKS, 256, 0, stream>>>(x, wbf, h, ei + E_EDGES, deg);
  k_scan<<<98, 256, 0, stream>>>(deg, part, bsum, bar, rowptr, cursor);
  k_fill<<<NIDX, 256, 0, stream>>>(ei, cursor, srcs);
  const float* dinv = (const float*)deg;
  k_agg<<<N_NODES / 4, 256, 0, stream>>>(rowptr, srcs, dinv, h, bias, out);
}